// Round 5
// baseline (19152.098 us; speedup 1.0000x reference)
//
#include <hip/hip_runtime.h>
#include <math.h>

#define N_NODES 100000
#define N_EDGES 3200000
#define BS 256
#define CAP_SHIFT 7            // 128 bucket slots per node; max deg ~59
#define CAP (1 << CAP_SHIFT)
#define OFF1 800000            // group-array offsets (floats) inside state buffers
#define OFF2 1600000

// ==================== deterministic all-f32 data path ====================
// Rounding-matched to the numpy reference (absmax 0 at r14/r16/r17):
//  - bucket sums in ascending edge-id order (np.add.at semantics)
//  - products rounded separately from adds in the SpMV (norm*h then add)
//  - matmuls as ascending-ci fmaf chains from 0; acc adds in ascending k
//  - dis = 1/sqrtf
// EVERY fp chain must stay bit-identical: only ADDRESSES change across rounds.
//
// r18: XCD-channel-split props. blockIdx%8 round-robins over XCDs (m157
// basis), so grid = (group x row-tile) with group from blockIdx%8 puts each
// <=3.2MB channel-group array on a disjoint XCD set -> per-XCD gather
// footprint fits 4MB L2 -> within-pass reuse becomes L2 hits (vs ~3.3TB/s
// LLC). One pass, all lanes parallel (r16 lesson). Matmul becomes a prop
// EPILOGUE: step k adds m_{k-1} from pm1 (completed last launch, race-free),
// co-shares split across groups; m_{K-1} folds into silu/final. pk stream is
// nontemporal so it cannot evict the resident arrays.
// State layouts: L1 S2 (0.8MB); L2 {8ch S8 @0 | 6ch+2pad S8 @OFF1};
// L3 {8 S8 @0 | 8 S8 @OFF1 | 4 S4 @OFF2}. accA pads memset to 0 once.

__global__ void scan_partial_kernel(const int* __restrict__ cnt, int* __restrict__ bsums) {
    __shared__ int lds[256];
    int tid = threadIdx.x;
    int base = blockIdx.x * 1024 + tid * 4;
    int s = 0;
#pragma unroll
    for (int i = 0; i < 4; ++i) s += (base + i < N_NODES) ? cnt[base + i] : 0;
    lds[tid] = s;
    __syncthreads();
    for (int off = 128; off > 0; off >>= 1) {
        if (tid < off) lds[tid] += lds[tid + off];
        __syncthreads();
    }
    if (tid == 0) bsums[blockIdx.x] = lds[0];
}

__global__ void scan_bsums_kernel(int* __restrict__ bsums, int nb, int* __restrict__ total_out) {
    if (threadIdx.x == 0 && blockIdx.x == 0) {
        int acc = 0;
        for (int b = 0; b < nb; ++b) {
            int v = bsums[b];
            bsums[b] = acc;
            acc += v;
        }
        *total_out = acc;
    }
}

__global__ void scan_final_kernel(const int* __restrict__ cnt, const int* __restrict__ bsums,
                                  int* __restrict__ rp) {
    __shared__ int lds[256];
    int tid = threadIdx.x;
    int base = blockIdx.x * 1024 + tid * 4;
    int v[4];
    int ts = 0;
#pragma unroll
    for (int i = 0; i < 4; ++i) {
        v[i] = (base + i < N_NODES) ? cnt[base + i] : 0;
        ts += v[i];
    }
    lds[tid] = ts;
    __syncthreads();
    for (int off = 1; off < 256; off <<= 1) {
        int t = (tid >= off) ? lds[tid - off] : 0;
        __syncthreads();
        lds[tid] += t;
        __syncthreads();
    }
    int run = lds[tid] - ts + bsums[blockIdx.x];
#pragma unroll
    for (int i = 0; i < 4; ++i) {
        if (base + i < N_NODES) rp[base + i] = run;
        run += v[i];
    }
}

// ONE edge pass: scatter edge ids into fixed-capacity per-node buckets for both
// src and dst keys; the atomic cursors ARE the per-node counts afterwards.
__global__ void fill_direct_kernel(const int* __restrict__ src, const int* __restrict__ dst,
                                   int* __restrict__ cnt_s, int* __restrict__ cnt_d,
                                   int* __restrict__ bkt_s, int* __restrict__ bkt_d) {
    int e = blockIdx.x * blockDim.x + threadIdx.x;
    if (e >= N_EDGES) return;
    int s = src[e];
    int d = dst[e];
    int slot_s = atomicAdd(&cnt_s[s], 1);
    bkt_s[((size_t)s << CAP_SHIFT) + slot_s] = e;
    int slot_d = atomicAdd(&cnt_d[d], 1);
    bkt_d[((size_t)d << CAP_SHIFT) + slot_d] = e;
}

// per-row rank-selection sort by edge id, row staged in LDS (64 threads x
// 65-int padded rows -> conflict-free; 16.6KB/block). Fallback for c>64.
__global__ __launch_bounds__(64) void sort_rows_lds_kernel(
    const int* __restrict__ cnt, const int* __restrict__ rp,
    const int* __restrict__ bkt, int* __restrict__ sorted) {
    __shared__ int lrow[64][65];
    int n = blockIdx.x * 64 + threadIdx.x;
    if (n >= N_NODES) return;
    int c = cnt[n];
    const int* row = bkt + ((size_t)n << CAP_SHIFT);
    int beg = rp[n];
    if (c <= 64) {
        int* lr = lrow[threadIdx.x];
        for (int i = 0; i < c; ++i) lr[i] = row[i];
        for (int i = 0; i < c; ++i) {
            int v = lr[i];
            int rk = 0;
            for (int j = 0; j < c; ++j) rk += (lr[j] < v);
            sorted[beg + rk] = v;
        }
    } else {
        for (int i = 0; i < c; ++i) {
            int v = row[i];
            int rk = 0;
            for (int j = 0; j < c; ++j) rk += (row[j] < v);
            sorted[beg + rk] = v;
        }
    }
}

// dis[n] = 1/sqrtf(f32 sum of w over src-row n, ascending edge id), 0 if deg<=0
__global__ void deg_dis_kernel(const int* __restrict__ rp_src, const int* __restrict__ sorted,
                               const float* __restrict__ w, float* __restrict__ dis) {
#pragma clang fp contract(off)
    {
        int n = blockIdx.x * blockDim.x + threadIdx.x;
        if (n >= N_NODES) return;
        float d = 0.f;
        int beg = rp_src[n], end = rp_src[n + 1];
        for (int j = beg; j < end; ++j) d = d + w[sorted[j]];
        dis[n] = (d > 0.f) ? (1.0f / sqrtf(d)) : 0.f;
    }
}

// packed[j] = {src, ((-dis[s]) * w) * dis[d]}
__global__ void csr_fill_kernel(const int* __restrict__ sorted, const int* __restrict__ src,
                                const int* __restrict__ dst, const float* __restrict__ w,
                                const float* __restrict__ dis, int2* __restrict__ packed) {
#pragma clang fp contract(off)
    {
        int j = blockIdx.x * blockDim.x + threadIdx.x;
        if (j >= N_EDGES) return;
        int e = sorted[j];
        int s = src[e], d = dst[e];
        float cw = ((-dis[s]) * w[e]) * dis[d];
        packed[j] = make_int2(s, __float_as_int(cw));
    }
}

// ==================== split-layout addressing ====================
__device__ __forceinline__ size_t addrA(int n, int c) {  // 14ch {8|6+2pad}
    return (c < 8) ? ((size_t)n * 8 + c) : (OFF1 + (size_t)n * 8 + (c - 8));
}
__device__ __forceinline__ size_t addrB(int n, int c) {  // 20ch {8|8|4}
    return (c < 8) ? ((size_t)n * 8 + c)
         : (c < 16) ? (OFF1 + (size_t)n * 8 + (c - 8))
                    : (OFF2 + (size_t)n * 4 + (c - 16));
}

// nontemporal pk record load (int2 as u64: low=src, high=w bits)
__device__ __forceinline__ void pkload(const int2* __restrict__ pk, int j,
                                       int& s, float& w) {
    unsigned long long u = __builtin_nontemporal_load(
        reinterpret_cast<const unsigned long long*>(pk + j));
    s = (int)(unsigned)(u & 0xffffffffull);
    w = __int_as_float((unsigned)(u >> 32));
}

// ==================== gather chains (ascending edge id, mul-then-add) ====================
template <int S>
__device__ __forceinline__ void gather4_u8(const float* __restrict__ a, int c0,
                                           const int2* __restrict__ pk, int beg, int end,
                                           float s[4]) {
#pragma clang fp contract(off)
    {
        int j = beg;
        for (; j + 7 < end; j += 8) {
            int e0, e1, e2, e3, e4, e5, e6, e7;
            float w0, w1, w2, w3, w4, w5, w6, w7;
            pkload(pk, j, e0, w0); pkload(pk, j + 1, e1, w1);
            pkload(pk, j + 2, e2, w2); pkload(pk, j + 3, e3, w3);
            pkload(pk, j + 4, e4, w4); pkload(pk, j + 5, e5, w5);
            pkload(pk, j + 6, e6, w6); pkload(pk, j + 7, e7, w7);
            const float4 q0 = *reinterpret_cast<const float4*>(a + (size_t)e0 * S + c0);
            const float4 q1 = *reinterpret_cast<const float4*>(a + (size_t)e1 * S + c0);
            const float4 q2 = *reinterpret_cast<const float4*>(a + (size_t)e2 * S + c0);
            const float4 q3 = *reinterpret_cast<const float4*>(a + (size_t)e3 * S + c0);
            const float4 q4 = *reinterpret_cast<const float4*>(a + (size_t)e4 * S + c0);
            const float4 q5 = *reinterpret_cast<const float4*>(a + (size_t)e5 * S + c0);
            const float4 q6 = *reinterpret_cast<const float4*>(a + (size_t)e6 * S + c0);
            const float4 q7 = *reinterpret_cast<const float4*>(a + (size_t)e7 * S + c0);
            s[0] = s[0] + (w0 * q0.x); s[1] = s[1] + (w0 * q0.y);
            s[2] = s[2] + (w0 * q0.z); s[3] = s[3] + (w0 * q0.w);
            s[0] = s[0] + (w1 * q1.x); s[1] = s[1] + (w1 * q1.y);
            s[2] = s[2] + (w1 * q1.z); s[3] = s[3] + (w1 * q1.w);
            s[0] = s[0] + (w2 * q2.x); s[1] = s[1] + (w2 * q2.y);
            s[2] = s[2] + (w2 * q2.z); s[3] = s[3] + (w2 * q2.w);
            s[0] = s[0] + (w3 * q3.x); s[1] = s[1] + (w3 * q3.y);
            s[2] = s[2] + (w3 * q3.z); s[3] = s[3] + (w3 * q3.w);
            s[0] = s[0] + (w4 * q4.x); s[1] = s[1] + (w4 * q4.y);
            s[2] = s[2] + (w4 * q4.z); s[3] = s[3] + (w4 * q4.w);
            s[0] = s[0] + (w5 * q5.x); s[1] = s[1] + (w5 * q5.y);
            s[2] = s[2] + (w5 * q5.z); s[3] = s[3] + (w5 * q5.w);
            s[0] = s[0] + (w6 * q6.x); s[1] = s[1] + (w6 * q6.y);
            s[2] = s[2] + (w6 * q6.z); s[3] = s[3] + (w6 * q6.w);
            s[0] = s[0] + (w7 * q7.x); s[1] = s[1] + (w7 * q7.y);
            s[2] = s[2] + (w7 * q7.z); s[3] = s[3] + (w7 * q7.w);
        }
        for (; j + 3 < end; j += 4) {
            int e0, e1, e2, e3;
            float w0, w1, w2, w3;
            pkload(pk, j, e0, w0); pkload(pk, j + 1, e1, w1);
            pkload(pk, j + 2, e2, w2); pkload(pk, j + 3, e3, w3);
            const float4 q0 = *reinterpret_cast<const float4*>(a + (size_t)e0 * S + c0);
            const float4 q1 = *reinterpret_cast<const float4*>(a + (size_t)e1 * S + c0);
            const float4 q2 = *reinterpret_cast<const float4*>(a + (size_t)e2 * S + c0);
            const float4 q3 = *reinterpret_cast<const float4*>(a + (size_t)e3 * S + c0);
            s[0] = s[0] + (w0 * q0.x); s[1] = s[1] + (w0 * q0.y);
            s[2] = s[2] + (w0 * q0.z); s[3] = s[3] + (w0 * q0.w);
            s[0] = s[0] + (w1 * q1.x); s[1] = s[1] + (w1 * q1.y);
            s[2] = s[2] + (w1 * q1.z); s[3] = s[3] + (w1 * q1.w);
            s[0] = s[0] + (w2 * q2.x); s[1] = s[1] + (w2 * q2.y);
            s[2] = s[2] + (w2 * q2.z); s[3] = s[3] + (w2 * q2.w);
            s[0] = s[0] + (w3 * q3.x); s[1] = s[1] + (w3 * q3.y);
            s[2] = s[2] + (w3 * q3.z); s[3] = s[3] + (w3 * q3.w);
        }
        for (; j < end; ++j) {
            int e;
            float w;
            pkload(pk, j, e, w);
            const float4 q = *reinterpret_cast<const float4*>(a + (size_t)e * S + c0);
            s[0] = s[0] + (w * q.x); s[1] = s[1] + (w * q.y);
            s[2] = s[2] + (w * q.z); s[3] = s[3] + (w * q.w);
        }
    }
}

__device__ __forceinline__ void gather2_u8(const float* __restrict__ a,
                                           const int2* __restrict__ pk, int beg, int end,
                                           float s[2]) {
#pragma clang fp contract(off)
    {
        int j = beg;
        for (; j + 7 < end; j += 8) {
            int e0, e1, e2, e3, e4, e5, e6, e7;
            float w0, w1, w2, w3, w4, w5, w6, w7;
            pkload(pk, j, e0, w0); pkload(pk, j + 1, e1, w1);
            pkload(pk, j + 2, e2, w2); pkload(pk, j + 3, e3, w3);
            pkload(pk, j + 4, e4, w4); pkload(pk, j + 5, e5, w5);
            pkload(pk, j + 6, e6, w6); pkload(pk, j + 7, e7, w7);
            const float2 q0 = *reinterpret_cast<const float2*>(a + (size_t)e0 * 2);
            const float2 q1 = *reinterpret_cast<const float2*>(a + (size_t)e1 * 2);
            const float2 q2 = *reinterpret_cast<const float2*>(a + (size_t)e2 * 2);
            const float2 q3 = *reinterpret_cast<const float2*>(a + (size_t)e3 * 2);
            const float2 q4 = *reinterpret_cast<const float2*>(a + (size_t)e4 * 2);
            const float2 q5 = *reinterpret_cast<const float2*>(a + (size_t)e5 * 2);
            const float2 q6 = *reinterpret_cast<const float2*>(a + (size_t)e6 * 2);
            const float2 q7 = *reinterpret_cast<const float2*>(a + (size_t)e7 * 2);
            s[0] = s[0] + (w0 * q0.x); s[1] = s[1] + (w0 * q0.y);
            s[0] = s[0] + (w1 * q1.x); s[1] = s[1] + (w1 * q1.y);
            s[0] = s[0] + (w2 * q2.x); s[1] = s[1] + (w2 * q2.y);
            s[0] = s[0] + (w3 * q3.x); s[1] = s[1] + (w3 * q3.y);
            s[0] = s[0] + (w4 * q4.x); s[1] = s[1] + (w4 * q4.y);
            s[0] = s[0] + (w5 * q5.x); s[1] = s[1] + (w5 * q5.y);
            s[0] = s[0] + (w6 * q6.x); s[1] = s[1] + (w6 * q6.y);
            s[0] = s[0] + (w7 * q7.x); s[1] = s[1] + (w7 * q7.y);
        }
        for (; j + 3 < end; j += 4) {
            int e0, e1, e2, e3;
            float w0, w1, w2, w3;
            pkload(pk, j, e0, w0); pkload(pk, j + 1, e1, w1);
            pkload(pk, j + 2, e2, w2); pkload(pk, j + 3, e3, w3);
            const float2 q0 = *reinterpret_cast<const float2*>(a + (size_t)e0 * 2);
            const float2 q1 = *reinterpret_cast<const float2*>(a + (size_t)e1 * 2);
            const float2 q2 = *reinterpret_cast<const float2*>(a + (size_t)e2 * 2);
            const float2 q3 = *reinterpret_cast<const float2*>(a + (size_t)e3 * 2);
            s[0] = s[0] + (w0 * q0.x); s[1] = s[1] + (w0 * q0.y);
            s[0] = s[0] + (w1 * q1.x); s[1] = s[1] + (w1 * q1.y);
            s[0] = s[0] + (w2 * q2.x); s[1] = s[1] + (w2 * q2.y);
            s[0] = s[0] + (w3 * q3.x); s[1] = s[1] + (w3 * q3.y);
        }
        for (; j < end; ++j) {
            int e;
            float w;
            pkload(pk, j, e, w);
            const float2 q = *reinterpret_cast<const float2*>(a + (size_t)e * 2);
            s[0] = s[0] + (w * q.x); s[1] = s[1] + (w * q.y);
        }
    }
}

// ==================== XCD-channel-split prop (+ deferred-mm epilogue) ====================
// step k (1-based): tx_k = prop(pm1) [k==1] or 2*prop(pm1)-pm2 [k>=2];
// epilogue adds m_{k-1} = chain(pm1, W+(k-1)*CIN*COUT) into acc (assign at k==1).
template <int LAYER>
__global__ __launch_bounds__(256) void prop_kernel(
    const int* __restrict__ rp, const int2* __restrict__ pk,
    const float* __restrict__ pm1, const float* __restrict__ pm2,
    const float* __restrict__ W, int k,
    float* __restrict__ tx, float* __restrict__ acc) {
#pragma clang fp contract(off)
    {
        constexpr int CIN = (LAYER == 1) ? 2 : ((LAYER == 2) ? 14 : 20);
        constexpr int COUT = (LAYER == 1) ? 14 : ((LAYER == 2) ? 20 : 27);
        const float* Wk = W + (size_t)(k - 1) * CIN * COUT;
        const int rec = (k >= 2);

        int n, g, lane;
        if constexpr (LAYER == 1) {
            g = 0;
            lane = 0;
            n = blockIdx.x * 256 + threadIdx.x;
        } else if constexpr (LAYER == 2) {
            int b = blockIdx.x;
            int xslot = b & 7;
            g = xslot & 1;
            int tile = (b >> 3) * 4 + (xslot >> 1);
            lane = threadIdx.x & 1;
            n = tile * 128 + (threadIdx.x >> 1);
        } else {
            int b = blockIdx.x;
            int xslot = b & 7;
            int p = b >> 3;
            if (xslot < 3) { g = 0; int tile = p * 3 + xslot;
                if (tile >= 782) return;
                lane = threadIdx.x & 1; n = tile * 128 + (threadIdx.x >> 1); }
            else if (xslot < 6) { g = 1; int tile = p * 3 + (xslot - 3);
                if (tile >= 782) return;
                lane = threadIdx.x & 1; n = tile * 128 + (threadIdx.x >> 1); }
            else { g = 2; int tile = p * 2 + (xslot - 6);
                if (tile >= 391) return;
                lane = 0; n = tile * 256 + threadIdx.x; }
        }
        if (n >= N_NODES) return;
        int beg = rp[n], end = rp[n + 1];

        // ---- gather + recurrence + tx write (group-local addresses) ----
        if constexpr (LAYER == 1) {
            float s[2] = {0.f, 0.f};
            gather2_u8(pm1, pk, beg, end, s);
            float t0v, t1v;
            if (rec) {
                float p0 = __builtin_nontemporal_load(pm2 + (size_t)n * 2);
                float p1 = __builtin_nontemporal_load(pm2 + (size_t)n * 2 + 1);
                t0v = 2.f * s[0] - p0;
                t1v = 2.f * s[1] - p1;
            } else { t0v = s[0]; t1v = s[1]; }
            __builtin_nontemporal_store(t0v, tx + (size_t)n * 2);
            __builtin_nontemporal_store(t1v, tx + (size_t)n * 2 + 1);
        } else {
            size_t goff = (g == 0) ? 0 : ((g == 1) ? (size_t)OFF1 : (size_t)OFF2);
            int S = (LAYER == 3 && g == 2) ? 4 : 8;
            int c0 = lane * 4;
            float s[4] = {0.f, 0.f, 0.f, 0.f};
            if (LAYER == 3 && g == 2) gather4_u8<4>(pm1 + goff, 0, pk, beg, end, s);
            else gather4_u8<8>(pm1 + goff, c0, pk, beg, end, s);
            size_t base = goff + (size_t)n * S + c0;
            float t[4];
            if (rec) {
                float p0 = __builtin_nontemporal_load(pm2 + base);
                float p1 = __builtin_nontemporal_load(pm2 + base + 1);
                float p2 = __builtin_nontemporal_load(pm2 + base + 2);
                float p3 = __builtin_nontemporal_load(pm2 + base + 3);
                t[0] = 2.f * s[0] - p0; t[1] = 2.f * s[1] - p1;
                t[2] = 2.f * s[2] - p2; t[3] = 2.f * s[3] - p3;
            } else {
                t[0] = s[0]; t[1] = s[1]; t[2] = s[2]; t[3] = s[3];
            }
            __builtin_nontemporal_store(t[0], tx + base);
            __builtin_nontemporal_store(t[1], tx + base + 1);
            __builtin_nontemporal_store(t[2], tx + base + 2);
            __builtin_nontemporal_store(t[3], tx + base + 3);
        }

        // ---- epilogue: acc op m_{k-1} from full pm1 row (race-free: pm1 done) ----
        float hv[CIN];
        if constexpr (LAYER == 1) {
            hv[0] = __builtin_nontemporal_load(pm1 + (size_t)n * 2);
            hv[1] = __builtin_nontemporal_load(pm1 + (size_t)n * 2 + 1);
        } else if constexpr (LAYER == 2) {
#pragma unroll
            for (int i = 0; i < 8; ++i) hv[i] = __builtin_nontemporal_load(pm1 + (size_t)n * 8 + i);
#pragma unroll
            for (int i = 0; i < 6; ++i)
                hv[8 + i] = __builtin_nontemporal_load(pm1 + OFF1 + (size_t)n * 8 + i);
        } else {
#pragma unroll
            for (int i = 0; i < 8; ++i) hv[i] = __builtin_nontemporal_load(pm1 + (size_t)n * 8 + i);
#pragma unroll
            for (int i = 0; i < 8; ++i)
                hv[8 + i] = __builtin_nontemporal_load(pm1 + OFF1 + (size_t)n * 8 + i);
#pragma unroll
            for (int i = 0; i < 4; ++i)
                hv[16 + i] = __builtin_nontemporal_load(pm1 + OFF2 + (size_t)n * 4 + i);
        }
        int co0, nco;
        if constexpr (LAYER == 1) { co0 = 0; nco = 14; }
        else if constexpr (LAYER == 2) { co0 = g * 10 + lane * 5; nco = 5; }
        else {
            if (g < 2) { co0 = g * 9 + lane * 5; nco = lane ? 4 : 5; }
            else { co0 = 18; nco = 9; }
        }
        for (int c = 0; c < nco; ++c) {
            int co = co0 + c;
            float m = 0.f;
#pragma unroll
            for (int ci = 0; ci < CIN; ++ci) m = fmaf(hv[ci], Wk[ci * COUT + co], m);
            size_t a;
            if constexpr (LAYER == 1) a = addrA(n, co);
            else if constexpr (LAYER == 2) a = addrB(n, co);
            else a = (size_t)n * 28 + co;
            if (k == 1) {
                __builtin_nontemporal_store(m, acc + a);
            } else {
                float old = __builtin_nontemporal_load(acc + a);
                __builtin_nontemporal_store(old + m, acc + a);
            }
        }
    }
}

// silu kernels: acc' = acc + m_{K-1}; x = acc' + b; silu — chains as r14.
__global__ void silu1_kernel(float* __restrict__ acc, const float* __restrict__ txl,
                             const float* __restrict__ Wl, const float* __restrict__ b) {
#pragma clang fp contract(off)
    {
        int t = blockIdx.x * blockDim.x + threadIdx.x;
        if (t >= N_NODES * 14) return;
        int n = t / 14, c = t - n * 14;
        float h0 = txl[(size_t)n * 2], h1 = txl[(size_t)n * 2 + 1];
        float m = 0.f;
        m = fmaf(h0, Wl[c], m);
        m = fmaf(h1, Wl[14 + c], m);
        size_t a = addrA(n, c);
        float v = acc[a] + m;
        float x = v + b[c];
        float sig = 1.f / (1.f + expf(-x));
        acc[a] = x * sig;
    }
}

__global__ void silu2_kernel(float* __restrict__ acc, const float* __restrict__ txl,
                             const float* __restrict__ Wl, const float* __restrict__ b) {
#pragma clang fp contract(off)
    {
        int t = blockIdx.x * blockDim.x + threadIdx.x;
        if (t >= N_NODES * 20) return;
        int n = t / 20, c = t - n * 20;
        float m = 0.f;
#pragma unroll
        for (int ci = 0; ci < 14; ++ci) {
            float hvv = txl[addrA(n, ci)];
            m = fmaf(hvv, Wl[ci * 20 + c], m);
        }
        size_t a = addrB(n, c);
        float v = acc[a] + m;
        float x = v + b[c];
        float sig = 1.f / (1.f + expf(-x));
        acc[a] = x * sig;
    }
}

// final: acc' = acc + m_{K-1}; silu(acc'+b3); W4 dot; sigmoid
__global__ void final_kernel(const float* __restrict__ acc, const float* __restrict__ txl,
                             const float* __restrict__ Wl, const float* __restrict__ b3,
                             const float* __restrict__ W4, float* __restrict__ out) {
#pragma clang fp contract(off)
    {
        int n = blockIdx.x * blockDim.x + threadIdx.x;
        if (n >= N_NODES) return;
        float hv[20];
#pragma unroll
        for (int i = 0; i < 20; ++i) hv[i] = txl[addrB(n, i)];
        float mo = 0.f;
#pragma unroll
        for (int c = 0; c < 27; ++c) {
            float m = 0.f;
#pragma unroll
            for (int ci = 0; ci < 20; ++ci) m = fmaf(hv[ci], Wl[ci * 27 + c], m);
            float v = acc[(size_t)n * 28 + c] + m;
            float x = v + b3[c];
            float sig = 1.f / (1.f + expf(-x));
            float hq = x * sig;
            mo = fmaf(hq, W4[c], mo);
        }
        out[n] = 1.f / (1.f + expf(-mo));
    }
}

__global__ void signal_kernel(float* __restrict__ out, float val) {
    int n = blockIdx.x * blockDim.x + threadIdx.x;
    if (n < N_NODES) out[n] = val;
}

// ==================== host driver ====================

static void run_scan(const int* cnt, int* bsums, int* rp, hipStream_t stream) {
    const int nb = (N_NODES + 1023) / 1024;  // 98
    scan_partial_kernel<<<nb, 256, 0, stream>>>(cnt, bsums);
    scan_bsums_kernel<<<1, 64, 0, stream>>>(bsums, nb, rp + N_NODES);
    scan_final_kernel<<<nb, 256, 0, stream>>>(cnt, bsums, rp);
}

template <int LAYER>
static const float* run_layer_x(int K, const float* h_in, const float* W, float* acc,
                                float* b0, float* b1, float* b2, const int* rp,
                                const int2* pk, hipStream_t stream) {
    const int grid = (LAYER == 1) ? 391 : ((LAYER == 2) ? 1568 : 2088);
    float* bufs[3] = {b0, b1, b2};
    const float* pm1 = h_in;
    const float* pm2 = nullptr;
    for (int k = 1; k < K; ++k) {
        float* outb = bufs[(k - 1) % 3];
        prop_kernel<LAYER><<<grid, 256, 0, stream>>>(rp, pk, pm1, pm2, W, k, outb, acc);
        pm2 = pm1;
        pm1 = outb;
    }
    return pm1;  // tx_{K-1}
}

extern "C" void kernel_launch(void* const* d_in, const int* in_sizes, int n_in, void* d_out,
                              int out_size, void* d_ws, size_t ws_size, hipStream_t stream) {
    const float* x  = (const float*)d_in[0];
    const int* idx  = (const int*)d_in[1];
    const float* ew = (const float*)d_in[2];
    const float* W1 = (const float*)d_in[3];
    const float* b1 = (const float*)d_in[4];
    const float* W2 = (const float*)d_in[5];
    const float* b2 = (const float*)d_in[6];
    const float* W3 = (const float*)d_in[7];
    const float* b3 = (const float*)d_in[8];
    const float* W4 = (const float*)d_in[9];
    float* out = (float*)d_out;
    (void)in_sizes; (void)n_in; (void)out_size;

    const int* src = idx;
    const int* dst = idx + N_EDGES;

    // workspace carve-up (256B aligned) — ~196 MB (budget ~272 MB)
    size_t off = 0;
    auto alloc = [&](size_t bytes) {
        size_t o = off;
        off = (off + bytes + 255) & ~(size_t)255;
        return o;
    };
    char* ws = (char*)d_ws;
    int*   cnt_s   = (int*)(ws + alloc(N_NODES * 4));          // fill cursors == counts
    int*   cnt_d   = (int*)(ws + alloc(N_NODES * 4));
    int*   rp_src  = (int*)(ws + alloc((N_NODES + 1) * 4));
    int*   rp_dst  = (int*)(ws + alloc((N_NODES + 1) * 4));
    float* dis     = (float*)(ws + alloc(N_NODES * 4));
    int*   bsums   = (int*)(ws + alloc(512));
    int2*  packed  = (int2*)(ws + alloc((size_t)N_EDGES * 8));     // 25.6MB
    // layer pool (contiguous). Setup aliases sorted_s@+0, sorted_d@+16MB.
    const size_t pool_off = alloc(0);
    float* t0      = (float*)(ws + alloc((size_t)2000000 * 4));    // tx bufs, 8MB each
    float* t1      = (float*)(ws + alloc((size_t)2000000 * 4));
    float* t2      = (float*)(ws + alloc((size_t)2000000 * 4));
    float* accA    = (float*)(ws + alloc((size_t)1600000 * 4));    // L1 out {8|6+2pad} 6.4MB
    float* accB    = (float*)(ws + alloc((size_t)2000000 * 4));    // L2 out {8|8|4} 8MB
    float* accC    = (float*)(ws + alloc((size_t)N_NODES * 28 * 4));  // L3 out row28 11.2MB
    int*   bkt_s   = (int*)(ws + alloc((size_t)N_NODES * CAP * 4));   // 51.2MB
    int*   bkt_d   = (int*)(ws + alloc((size_t)N_NODES * CAP * 4));   // 51.2MB
    const size_t NEED = off;
    char* pool = ws + pool_off;
    int* sorted_s = (int*)(pool);                        // consumed by deg_dis
    int* sorted_d = (int*)(pool + ((size_t)16 << 20));   // consumed by csr_fill

    int gE = (N_EDGES + BS - 1) / BS;
    int gN = (N_NODES + BS - 1) / BS;

    if (ws_size < NEED) {  // diagnostic: reveal ws_size in MB via absmax
        signal_kernel<<<gN, BS, 0, stream>>>(
            out, 6000.0f + (float)(ws_size / (1024.0 * 1024.0)));
        return;
    }

    // ---- setup: single-pass fill (r14), LDS rank-sort, dis, packed ----
    (void)hipMemsetAsync(cnt_s, 0, N_NODES * 4, stream);
    (void)hipMemsetAsync(cnt_d, 0, N_NODES * 4, stream);
    fill_direct_kernel<<<gE, BS, 0, stream>>>(src, dst, cnt_s, cnt_d, bkt_s, bkt_d);
    run_scan(cnt_s, bsums, rp_src, stream);
    run_scan(cnt_d, bsums, rp_dst, stream);
    const int gSort = (N_NODES + 63) / 64;
    sort_rows_lds_kernel<<<gSort, 64, 0, stream>>>(cnt_s, rp_src, bkt_s, sorted_s);
    deg_dis_kernel<<<gN, BS, 0, stream>>>(rp_src, sorted_s, ew, dis);
    sort_rows_lds_kernel<<<gSort, 64, 0, stream>>>(cnt_d, rp_dst, bkt_d, sorted_d);
    csr_fill_kernel<<<gE, BS, 0, stream>>>(sorted_d, src, dst, ew, dis, packed);

    // accA pads (ch14,15) must be 0: they are gathered (f4) by L2 props.
    (void)hipMemsetAsync(accA, 0, (size_t)1600000 * 4, stream);

    // ---- layers ----
    const float* txl1 = run_layer_x<1>(39, x, W1, accA, t0, t1, t2, rp_dst, packed, stream);
    silu1_kernel<<<(N_NODES * 14 + BS - 1) / BS, BS, 0, stream>>>(
        accA, txl1, W1 + (size_t)38 * 2 * 14, b1);
    const float* txl2 = run_layer_x<2>(43, accA, W2, accB, t0, t1, t2, rp_dst, packed, stream);
    silu2_kernel<<<(N_NODES * 20 + BS - 1) / BS, BS, 0, stream>>>(
        accB, txl2, W2 + (size_t)42 * 14 * 20, b2);
    const float* txl3 = run_layer_x<3>(45, accB, W3, accC, t0, t1, t2, rp_dst, packed, stream);
    final_kernel<<<gN, BS, 0, stream>>>(accC, txl3, W3 + (size_t)44 * 20 * 27, b3, W4, out);
}

// Round 8
// 7683.642 us; speedup vs baseline: 2.4926x; 2.4926x over previous
//
// r19 resubmit (two prior submission-format failures; theory unchanged):
// r14-verbatim layer phase (best passing: 8148us) + LDS-staged rank-sort with
// fused deg/dis (src side) and fused packed-emit (dst side). The two 302us
// rank-sort dispatches (13% occupancy, c^2 global row re-reads) become
// LDS-local after a single row stage; deg_dis + csr_fill passes and both
// sorted_* buffers are deleted. fill_direct unchanged (~620us, atomic
// request-rate bound). Predict: sort+deg ~100us, sort+pack ~120us,
// total 8148 -> ~7.5-7.8ms.
#include <hip/hip_runtime.h>
#include <math.h>

#define N_NODES 100000
#define N_EDGES 3200000
#define BS 256
#define CAP_SHIFT 7            // 128 bucket slots per node; max deg ~59 (Poisson 32 + 6 sigma)
#define CAP (1 << CAP_SHIFT)

// ==================== deterministic all-f32 data path ====================
// Rounding-matched to the numpy reference (absmax 0 at r14/r16/r17):
//  - bucket sums in ascending edge-id order (np.add.at semantics)
//  - products rounded separately from adds in the SpMV (norm*h then add)
//  - matmuls as ascending-ci fmaf chains from 0; acc adds in ascending k
//  - dis = 1/sqrtf
// f64 is provably WRONG here. EVERY fp chain must stay bit-identical:
// parallelize only across independent chains; only ADDRESSES change.
//
// Perf ledger: r14 = 8148us (best). r16 sequential-group props = -37%
// (latency-bound: concurrency loss beats residency). r17 phased fill = null
// (fill is atomic-REQUEST-RATE bound, ~21G req/s). r18 nt-hints + scalar
// epilogue = -2.3x (nt on pk is poison).

__global__ void scan_partial_kernel(const int* __restrict__ cnt, int* __restrict__ bsums) {
    __shared__ int lds[256];
    int tid = threadIdx.x;
    int base = blockIdx.x * 1024 + tid * 4;
    int s = 0;
#pragma unroll
    for (int i = 0; i < 4; ++i) s += (base + i < N_NODES) ? cnt[base + i] : 0;
    lds[tid] = s;
    __syncthreads();
    for (int off = 128; off > 0; off >>= 1) {
        if (tid < off) lds[tid] += lds[tid + off];
        __syncthreads();
    }
    if (tid == 0) bsums[blockIdx.x] = lds[0];
}

__global__ void scan_bsums_kernel(int* __restrict__ bsums, int nb, int* __restrict__ total_out) {
    if (threadIdx.x == 0 && blockIdx.x == 0) {
        int acc = 0;
        for (int b = 0; b < nb; ++b) {
            int v = bsums[b];
            bsums[b] = acc;
            acc += v;
        }
        *total_out = acc;
    }
}

__global__ void scan_final_kernel(const int* __restrict__ cnt, const int* __restrict__ bsums,
                                  int* __restrict__ rp) {
    __shared__ int lds[256];
    int tid = threadIdx.x;
    int base = blockIdx.x * 1024 + tid * 4;
    int v[4];
    int ts = 0;
#pragma unroll
    for (int i = 0; i < 4; ++i) {
        v[i] = (base + i < N_NODES) ? cnt[base + i] : 0;
        ts += v[i];
    }
    lds[tid] = ts;
    __syncthreads();
    for (int off = 1; off < 256; off <<= 1) {
        int t = (tid >= off) ? lds[tid - off] : 0;
        __syncthreads();
        lds[tid] += t;
        __syncthreads();
    }
    int run = lds[tid] - ts + bsums[blockIdx.x];
#pragma unroll
    for (int i = 0; i < 4; ++i) {
        if (base + i < N_NODES) rp[base + i] = run;
        run += v[i];
    }
}

// ONE edge pass: scatter edge ids into fixed-capacity per-node buckets for both
// src and dst keys; the atomic cursors ARE the per-node counts afterwards.
__global__ void fill_direct_kernel(const int* __restrict__ src, const int* __restrict__ dst,
                                   int* __restrict__ cnt_s, int* __restrict__ cnt_d,
                                   int* __restrict__ bkt_s, int* __restrict__ bkt_d) {
    int e = blockIdx.x * blockDim.x + threadIdx.x;
    if (e >= N_EDGES) return;
    int s = src[e];
    int d = dst[e];
    int slot_s = atomicAdd(&cnt_s[s], 1);
    bkt_s[((size_t)s << CAP_SHIFT) + slot_s] = e;
    int slot_d = atomicAdd(&cnt_d[d], 1);
    bkt_d[((size_t)d << CAP_SHIFT) + slot_d] = e;
}

// src-side: LDS-staged rank-sort of the bucket row by edge id, then
// dis[n] = 1/sqrtf(sum of w in ascending edge-id order). No sorted buffer.
__global__ __launch_bounds__(64) void sort_deg_dis_kernel(
    const int* __restrict__ cnt, const int* __restrict__ bkt,
    const float* __restrict__ w, float* __restrict__ dis) {
#pragma clang fp contract(off)
    {
        __shared__ int lr[64][65];
        __shared__ int ls[64][65];
        int n = blockIdx.x * 64 + threadIdx.x;
        if (n >= N_NODES) return;
        int c = cnt[n];
        const int* row = bkt + ((size_t)n << CAP_SHIFT);
        float d = 0.f;
        if (c <= 64) {
            int* a = lr[threadIdx.x];
            int* b = ls[threadIdx.x];
            for (int i = 0; i < c; ++i) a[i] = row[i];
            for (int i = 0; i < c; ++i) {
                int v = a[i];
                int rk = 0;
                for (int j = 0; j < c; ++j) rk += (a[j] < v);
                b[rk] = v;
            }
            for (int r = 0; r < c; ++r) d = d + w[b[r]];
        } else {  // rare fallback (c in (64,128]): ordered O(c^2) from global
            for (int r = 0; r < c; ++r) {
                for (int i = 0; i < c; ++i) {
                    int v = row[i];
                    int rk = 0;
                    for (int j = 0; j < c; ++j) rk += (row[j] < v);
                    if (rk == r) { d = d + w[v]; break; }
                }
            }
        }
        dis[n] = (d > 0.f) ? (1.0f / sqrtf(d)) : 0.f;
    }
}

// dst-side: LDS-staged rank-sort, then directly emit
// packed[beg+r] = {src[e], ((-dis[s]) * w[e]) * dis[n]} (dst[e]==n).
__global__ __launch_bounds__(64) void sort_pack_kernel(
    const int* __restrict__ cnt, const int* __restrict__ rp,
    const int* __restrict__ bkt, const int* __restrict__ src,
    const float* __restrict__ w, const float* __restrict__ dis,
    int2* __restrict__ packed) {
#pragma clang fp contract(off)
    {
        __shared__ int lr[64][65];
        __shared__ int ls[64][65];
        int n = blockIdx.x * 64 + threadIdx.x;
        if (n >= N_NODES) return;
        int c = cnt[n];
        const int* row = bkt + ((size_t)n << CAP_SHIFT);
        int beg = rp[n];
        float din = dis[n];
        if (c <= 64) {
            int* a = lr[threadIdx.x];
            int* b = ls[threadIdx.x];
            for (int i = 0; i < c; ++i) a[i] = row[i];
            for (int i = 0; i < c; ++i) {
                int v = a[i];
                int rk = 0;
                for (int j = 0; j < c; ++j) rk += (a[j] < v);
                b[rk] = v;
            }
            for (int r = 0; r < c; ++r) {
                int e = b[r];
                int s = src[e];
                float cw = ((-dis[s]) * w[e]) * din;
                packed[beg + r] = make_int2(s, __float_as_int(cw));
            }
        } else {  // rare fallback
            for (int r = 0; r < c; ++r) {
                for (int i = 0; i < c; ++i) {
                    int v = row[i];
                    int rk = 0;
                    for (int j = 0; j < c; ++j) rk += (row[j] < v);
                    if (rk == r) {
                        int s = src[v];
                        float cw = ((-dis[s]) * w[v]) * din;
                        packed[beg + r] = make_int2(s, __float_as_int(cw));
                        break;
                    }
                }
            }
        }
    }
}

// ==================== per-layer kernels (r14-verbatim, f32, rounding-matched) ====================

// thread per (n,co): acc[n*SACC+co] = fmaf-chain over ci of hin[n*SIN+ci]*W0[ci,co]
template <int CIN, int COUT, int SIN, int SACC>
__global__ void layer_init_kernel(const float* __restrict__ hin, const float* __restrict__ W0,
                                  float* __restrict__ acc) {
    int t = blockIdx.x * blockDim.x + threadIdx.x;
    if (t >= N_NODES * COUT) return;
    int n = t / COUT, co = t - n * COUT;
    const float* hr = hin + (size_t)n * SIN;
    float m = 0.f;
#pragma unroll
    for (int ci = 0; ci < CIN; ++ci) m = fmaf(hr[ci], W0[ci * COUT + co], m);
    acc[(size_t)n * SACC + co] = m;
}

// Grouped-channel prop+matmul (r14). Block = R rows x LANES lanes; lane owns GS
// consecutive channels. Per-channel gather chains in ascending edge-id order
// (mul rounded then add); recurrence; LDS handoff; ascending-ci fmaf matmul
// chain; acc += m. Edge loop unrolled x8: 8 pk records + 8 gathers in flight.
template <int CIN, int COUT, int SIN, int SACC, int GS, int LANES, int R>
__global__ __launch_bounds__(LANES* R) void prop_mm_kernel(
    const int* __restrict__ rp, const int2* __restrict__ pk, const float* __restrict__ hin,
    const float* __restrict__ prev, const float* __restrict__ Wk, int rec,
    float* __restrict__ tx_out, float* __restrict__ acc) {
#pragma clang fp contract(off)
    {
        __shared__ float tls[R][LANES * GS];
        int r = threadIdx.x / LANES;
        int lane = threadIdx.x - r * LANES;
        int n = blockIdx.x * R + r;
        bool vn = (n < N_NODES);
        if (vn) {
            int c0 = lane * GS;
            float s[GS];
#pragma unroll
            for (int g = 0; g < GS; ++g) s[g] = 0.f;
            int beg = rp[n], end = rp[n + 1];
            int j = beg;
            if constexpr (GS == 4) {
                for (; j + 7 < end; j += 8) {
                    int2 p0 = pk[j];
                    int2 p1 = pk[j + 1];
                    int2 p2 = pk[j + 2];
                    int2 p3 = pk[j + 3];
                    int2 p4 = pk[j + 4];
                    int2 p5 = pk[j + 5];
                    int2 p6 = pk[j + 6];
                    int2 p7 = pk[j + 7];
                    const float4 q0 = *reinterpret_cast<const float4*>(hin + (size_t)p0.x * SIN + c0);
                    const float4 q1 = *reinterpret_cast<const float4*>(hin + (size_t)p1.x * SIN + c0);
                    const float4 q2 = *reinterpret_cast<const float4*>(hin + (size_t)p2.x * SIN + c0);
                    const float4 q3 = *reinterpret_cast<const float4*>(hin + (size_t)p3.x * SIN + c0);
                    const float4 q4 = *reinterpret_cast<const float4*>(hin + (size_t)p4.x * SIN + c0);
                    const float4 q5 = *reinterpret_cast<const float4*>(hin + (size_t)p5.x * SIN + c0);
                    const float4 q6 = *reinterpret_cast<const float4*>(hin + (size_t)p6.x * SIN + c0);
                    const float4 q7 = *reinterpret_cast<const float4*>(hin + (size_t)p7.x * SIN + c0);
                    float w0 = __int_as_float(p0.y), w1 = __int_as_float(p1.y);
                    float w2 = __int_as_float(p2.y), w3 = __int_as_float(p3.y);
                    float w4 = __int_as_float(p4.y), w5 = __int_as_float(p5.y);
                    float w6 = __int_as_float(p6.y), w7 = __int_as_float(p7.y);
                    s[0] = s[0] + (w0 * q0.x); s[1] = s[1] + (w0 * q0.y);
                    s[2] = s[2] + (w0 * q0.z); s[3] = s[3] + (w0 * q0.w);
                    s[0] = s[0] + (w1 * q1.x); s[1] = s[1] + (w1 * q1.y);
                    s[2] = s[2] + (w1 * q1.z); s[3] = s[3] + (w1 * q1.w);
                    s[0] = s[0] + (w2 * q2.x); s[1] = s[1] + (w2 * q2.y);
                    s[2] = s[2] + (w2 * q2.z); s[3] = s[3] + (w2 * q2.w);
                    s[0] = s[0] + (w3 * q3.x); s[1] = s[1] + (w3 * q3.y);
                    s[2] = s[2] + (w3 * q3.z); s[3] = s[3] + (w3 * q3.w);
                    s[0] = s[0] + (w4 * q4.x); s[1] = s[1] + (w4 * q4.y);
                    s[2] = s[2] + (w4 * q4.z); s[3] = s[3] + (w4 * q4.w);
                    s[0] = s[0] + (w5 * q5.x); s[1] = s[1] + (w5 * q5.y);
                    s[2] = s[2] + (w5 * q5.z); s[3] = s[3] + (w5 * q5.w);
                    s[0] = s[0] + (w6 * q6.x); s[1] = s[1] + (w6 * q6.y);
                    s[2] = s[2] + (w6 * q6.z); s[3] = s[3] + (w6 * q6.w);
                    s[0] = s[0] + (w7 * q7.x); s[1] = s[1] + (w7 * q7.y);
                    s[2] = s[2] + (w7 * q7.z); s[3] = s[3] + (w7 * q7.w);
                }
                for (; j + 3 < end; j += 4) {
                    int2 p0 = pk[j];
                    int2 p1 = pk[j + 1];
                    int2 p2 = pk[j + 2];
                    int2 p3 = pk[j + 3];
                    const float4 q0 = *reinterpret_cast<const float4*>(hin + (size_t)p0.x * SIN + c0);
                    const float4 q1 = *reinterpret_cast<const float4*>(hin + (size_t)p1.x * SIN + c0);
                    const float4 q2 = *reinterpret_cast<const float4*>(hin + (size_t)p2.x * SIN + c0);
                    const float4 q3 = *reinterpret_cast<const float4*>(hin + (size_t)p3.x * SIN + c0);
                    float w0 = __int_as_float(p0.y), w1 = __int_as_float(p1.y);
                    float w2 = __int_as_float(p2.y), w3 = __int_as_float(p3.y);
                    s[0] = s[0] + (w0 * q0.x); s[1] = s[1] + (w0 * q0.y);
                    s[2] = s[2] + (w0 * q0.z); s[3] = s[3] + (w0 * q0.w);
                    s[0] = s[0] + (w1 * q1.x); s[1] = s[1] + (w1 * q1.y);
                    s[2] = s[2] + (w1 * q1.z); s[3] = s[3] + (w1 * q1.w);
                    s[0] = s[0] + (w2 * q2.x); s[1] = s[1] + (w2 * q2.y);
                    s[2] = s[2] + (w2 * q2.z); s[3] = s[3] + (w2 * q2.w);
                    s[0] = s[0] + (w3 * q3.x); s[1] = s[1] + (w3 * q3.y);
                    s[2] = s[2] + (w3 * q3.z); s[3] = s[3] + (w3 * q3.w);
                }
                for (; j < end; ++j) {
                    int2 p = pk[j];
                    float w = __int_as_float(p.y);
                    const float4 q = *reinterpret_cast<const float4*>(hin + (size_t)p.x * SIN + c0);
                    s[0] = s[0] + (w * q.x); s[1] = s[1] + (w * q.y);
                    s[2] = s[2] + (w * q.z); s[3] = s[3] + (w * q.w);
                }
            } else {  // GS == 2
                for (; j + 7 < end; j += 8) {
                    int2 p0 = pk[j];
                    int2 p1 = pk[j + 1];
                    int2 p2 = pk[j + 2];
                    int2 p3 = pk[j + 3];
                    int2 p4 = pk[j + 4];
                    int2 p5 = pk[j + 5];
                    int2 p6 = pk[j + 6];
                    int2 p7 = pk[j + 7];
                    const float2 q0 = *reinterpret_cast<const float2*>(hin + (size_t)p0.x * SIN + c0);
                    const float2 q1 = *reinterpret_cast<const float2*>(hin + (size_t)p1.x * SIN + c0);
                    const float2 q2 = *reinterpret_cast<const float2*>(hin + (size_t)p2.x * SIN + c0);
                    const float2 q3 = *reinterpret_cast<const float2*>(hin + (size_t)p3.x * SIN + c0);
                    const float2 q4 = *reinterpret_cast<const float2*>(hin + (size_t)p4.x * SIN + c0);
                    const float2 q5 = *reinterpret_cast<const float2*>(hin + (size_t)p5.x * SIN + c0);
                    const float2 q6 = *reinterpret_cast<const float2*>(hin + (size_t)p6.x * SIN + c0);
                    const float2 q7 = *reinterpret_cast<const float2*>(hin + (size_t)p7.x * SIN + c0);
                    float w0 = __int_as_float(p0.y), w1 = __int_as_float(p1.y);
                    float w2 = __int_as_float(p2.y), w3 = __int_as_float(p3.y);
                    float w4 = __int_as_float(p4.y), w5 = __int_as_float(p5.y);
                    float w6 = __int_as_float(p6.y), w7 = __int_as_float(p7.y);
                    s[0] = s[0] + (w0 * q0.x); s[1] = s[1] + (w0 * q0.y);
                    s[0] = s[0] + (w1 * q1.x); s[1] = s[1] + (w1 * q1.y);
                    s[0] = s[0] + (w2 * q2.x); s[1] = s[1] + (w2 * q2.y);
                    s[0] = s[0] + (w3 * q3.x); s[1] = s[1] + (w3 * q3.y);
                    s[0] = s[0] + (w4 * q4.x); s[1] = s[1] + (w4 * q4.y);
                    s[0] = s[0] + (w5 * q5.x); s[1] = s[1] + (w5 * q5.y);
                    s[0] = s[0] + (w6 * q6.x); s[1] = s[1] + (w6 * q6.y);
                    s[0] = s[0] + (w7 * q7.x); s[1] = s[1] + (w7 * q7.y);
                }
                for (; j + 3 < end; j += 4) {
                    int2 p0 = pk[j];
                    int2 p1 = pk[j + 1];
                    int2 p2 = pk[j + 2];
                    int2 p3 = pk[j + 3];
                    const float2 q0 = *reinterpret_cast<const float2*>(hin + (size_t)p0.x * SIN + c0);
                    const float2 q1 = *reinterpret_cast<const float2*>(hin + (size_t)p1.x * SIN + c0);
                    const float2 q2 = *reinterpret_cast<const float2*>(hin + (size_t)p2.x * SIN + c0);
                    const float2 q3 = *reinterpret_cast<const float2*>(hin + (size_t)p3.x * SIN + c0);
                    float w0 = __int_as_float(p0.y), w1 = __int_as_float(p1.y);
                    float w2 = __int_as_float(p2.y), w3 = __int_as_float(p3.y);
                    s[0] = s[0] + (w0 * q0.x); s[1] = s[1] + (w0 * q0.y);
                    s[0] = s[0] + (w1 * q1.x); s[1] = s[1] + (w1 * q1.y);
                    s[0] = s[0] + (w2 * q2.x); s[1] = s[1] + (w2 * q2.y);
                    s[0] = s[0] + (w3 * q3.x); s[1] = s[1] + (w3 * q3.y);
                }
                for (; j < end; ++j) {
                    int2 p = pk[j];
                    float w = __int_as_float(p.y);
                    const float2 q = *reinterpret_cast<const float2*>(hin + (size_t)p.x * SIN + c0);
                    s[0] = s[0] + (w * q.x); s[1] = s[1] + (w * q.y);
                }
            }
            float t[GS];
            if (rec) {
#pragma unroll
                for (int g = 0; g < GS; ++g) t[g] = 2.f * s[g] - prev[(size_t)n * SIN + c0 + g];
            } else {
#pragma unroll
                for (int g = 0; g < GS; ++g) t[g] = s[g];
            }
#pragma unroll
            for (int g = 0; g < GS; ++g) tls[r][c0 + g] = t[g];
            if constexpr (GS == 4) {
                *reinterpret_cast<float4*>(tx_out + (size_t)n * SIN + c0) =
                    make_float4(t[0], t[1], t[2], t[3]);
            } else {
                *reinterpret_cast<float2*>(tx_out + (size_t)n * SIN + c0) =
                    make_float2(t[0], t[1]);
            }
        }
        __syncthreads();
        if (vn) {
            for (int co = lane; co < COUT; co += LANES) {
                float m = 0.f;
#pragma unroll
                for (int ci = 0; ci < CIN; ++ci) m = fmaf(tls[r][ci], Wk[ci * COUT + co], m);
                acc[(size_t)n * SACC + co] = acc[(size_t)n * SACC + co] + m;
            }
        }
    }
}

// a = silu(a + b) at padded stride S, real channels C only
template <int C, int S>
__global__ void silu_bias_kernel(float* __restrict__ a, const float* __restrict__ b) {
#pragma clang fp contract(off)
    {
        int t = blockIdx.x * blockDim.x + threadIdx.x;
        if (t >= N_NODES * C) return;
        int n = t / C, c = t - n * C;
        float x = a[(size_t)n * S + c] + b[c];
        float sig = 1.f / (1.f + expf(-x));
        a[(size_t)n * S + c] = x * sig;
    }
}

// fused: silu(acc+b3) -> W4 dot -> sigmoid. Chain per channel: x = acc+b3,
// sig, h = x*sig, then ascending-ci fmaf into the W4 dot — identical fp ops
// and order to silu_bias<27,28> followed by the old final_kernel.
__global__ void final_kernel(const float* __restrict__ acc, const float* __restrict__ b3,
                             const float* __restrict__ W4, float* __restrict__ out) {
#pragma clang fp contract(off)
    {
        int n = blockIdx.x * blockDim.x + threadIdx.x;
        if (n >= N_NODES) return;
        float m = 0.f;
#pragma unroll
        for (int ci = 0; ci < 27; ++ci) {
            float xv = acc[(size_t)n * 28 + ci] + b3[ci];
            float sig = 1.f / (1.f + expf(-xv));
            float hv = xv * sig;
            m = fmaf(hv, W4[ci], m);
        }
        out[n] = 1.f / (1.f + expf(-m));
    }
}

__global__ void signal_kernel(float* __restrict__ out, float val) {
    int n = blockIdx.x * blockDim.x + threadIdx.x;
    if (n < N_NODES) out[n] = val;
}

// ==================== host driver ====================

static void run_scan(const int* cnt, int* bsums, int* rp, hipStream_t stream) {
    const int nb = (N_NODES + 1023) / 1024;  // 98
    scan_partial_kernel<<<nb, 256, 0, stream>>>(cnt, bsums);
    scan_bsums_kernel<<<1, 64, 0, stream>>>(bsums, nb, rp + N_NODES);
    scan_final_kernel<<<nb, 256, 0, stream>>>(cnt, bsums, rp);
}

template <int CIN, int COUT, int SIN, int SACC, int GS, int LANES, int R>
static void run_layer(int K, const float* hin, const float* W, float* acc, float* b0, float* b1,
                      float* b2, const int* rp, const int2* pk, hipStream_t stream) {
    const int gInit = (N_NODES * COUT + BS - 1) / BS;
    const int gProp = (N_NODES + R - 1) / R;
    layer_init_kernel<CIN, COUT, SIN, SACC><<<gInit, BS, 0, stream>>>(hin, W, acc);
    if (K > 1) {
        float* bufs[3] = {b0, b1, b2};
        prop_mm_kernel<CIN, COUT, SIN, SACC, GS, LANES, R><<<gProp, LANES * R, 0, stream>>>(
            rp, pk, hin, nullptr, W + 1 * CIN * COUT, 0, bufs[0], acc);
        const float* pm2 = hin;      // tx_{k-2}
        const float* pm1 = bufs[0];  // tx_{k-1}
        for (int k = 2; k < K; ++k) {
            float* outb = bufs[(k - 1) % 3];  // k=2->b1, k=3->b2, k=4->b0, ...
            prop_mm_kernel<CIN, COUT, SIN, SACC, GS, LANES, R><<<gProp, LANES * R, 0, stream>>>(
                rp, pk, pm1, pm2, W + k * CIN * COUT, 1, outb, acc);
            pm2 = pm1;
            pm1 = outb;
        }
    }
}

extern "C" void kernel_launch(void* const* d_in, const int* in_sizes, int n_in, void* d_out,
                              int out_size, void* d_ws, size_t ws_size, hipStream_t stream) {
    const float* x  = (const float*)d_in[0];
    const int* idx  = (const int*)d_in[1];
    const float* ew = (const float*)d_in[2];
    const float* W1 = (const float*)d_in[3];
    const float* b1 = (const float*)d_in[4];
    const float* W2 = (const float*)d_in[5];
    const float* b2 = (const float*)d_in[6];
    const float* W3 = (const float*)d_in[7];
    const float* b3 = (const float*)d_in[8];
    const float* W4 = (const float*)d_in[9];
    float* out = (float*)d_out;
    (void)in_sizes; (void)n_in; (void)out_size;

    const int* src = idx;
    const int* dst = idx + N_EDGES;

    // workspace carve-up (256B aligned) — ~180 MB (budget ~272 MB)
    size_t off = 0;
    auto alloc = [&](size_t bytes) {
        size_t o = off;
        off = (off + bytes + 255) & ~(size_t)255;
        return o;
    };
    char* ws = (char*)d_ws;
    int*   cnt_s   = (int*)(ws + alloc(N_NODES * 4));          // fill cursors == counts
    int*   cnt_d   = (int*)(ws + alloc(N_NODES * 4));
    int*   rp_src  = (int*)(ws + alloc((N_NODES + 1) * 4));
    int*   rp_dst  = (int*)(ws + alloc((N_NODES + 1) * 4));
    float* dis     = (float*)(ws + alloc(N_NODES * 4));
    int*   bsums   = (int*)(ws + alloc(512));
    int2*  packed  = (int2*)(ws + alloc((size_t)N_EDGES * 8));     // 25.6MB
    float* t0      = (float*)(ws + alloc((size_t)N_NODES * 20 * 4));  // tx, stride<=20
    float* t1      = (float*)(ws + alloc((size_t)N_NODES * 20 * 4));
    float* t2      = (float*)(ws + alloc((size_t)N_NODES * 20 * 4));
    float* accA    = (float*)(ws + alloc((size_t)N_NODES * 16 * 4));  // L1 out, stride 16
    float* accB    = (float*)(ws + alloc((size_t)N_NODES * 20 * 4));  // L2 out, stride 20
    float* accC    = (float*)(ws + alloc((size_t)N_NODES * 28 * 4));  // L3 out, stride 28
    int*   bkt_s   = (int*)(ws + alloc((size_t)N_NODES * CAP * 4));   // 51.2MB
    int*   bkt_d   = (int*)(ws + alloc((size_t)N_NODES * CAP * 4));   // 51.2MB
    const size_t NEED = off;

    int gE = (N_EDGES + BS - 1) / BS;
    int gN = (N_NODES + BS - 1) / BS;
    const int gSort = (N_NODES + 63) / 64;

    if (ws_size < NEED) {  // diagnostic: reveal ws_size in MB via absmax
        signal_kernel<<<gN, BS, 0, stream>>>(
            out, 6000.0f + (float)(ws_size / (1024.0 * 1024.0)));
        return;
    }

    // ---- setup: fill, scans, fused sort+deg / sort+pack ----
    (void)hipMemsetAsync(cnt_s, 0, N_NODES * 4, stream);
    (void)hipMemsetAsync(cnt_d, 0, N_NODES * 4, stream);
    fill_direct_kernel<<<gE, BS, 0, stream>>>(src, dst, cnt_s, cnt_d, bkt_s, bkt_d);
    run_scan(cnt_s, bsums, rp_src, stream);
    run_scan(cnt_d, bsums, rp_dst, stream);
    sort_deg_dis_kernel<<<gSort, 64, 0, stream>>>(cnt_s, bkt_s, ew, dis);
    sort_pack_kernel<<<gSort, 64, 0, stream>>>(cnt_d, rp_dst, bkt_d, src, ew, dis, packed);

    // ---- layers (r14-verbatim) ----
    // L1: CIN=2 (x, stride 2), out accA stride 16; 1 lane x 256 rows (float2 gather)
    run_layer<2, 14, 2, 16, 2, 1, 256>(39, x, W1, accA, t0, t1, t2, rp_dst, packed, stream);
    silu_bias_kernel<14, 16><<<(N_NODES * 14 + BS - 1) / BS, BS, 0, stream>>>(accA, b1);
    // L2: CIN=14 @ stride 16 (64B rows), out accB stride 20; 4 lanes x 64 rows
    run_layer<14, 20, 16, 20, 4, 4, 64>(43, accA, W2, accB, t0, t1, t2, rp_dst, packed, stream);
    silu_bias_kernel<20, 20><<<(N_NODES * 20 + BS - 1) / BS, BS, 0, stream>>>(accB, b2);
    // L3: CIN=20 @ stride 20 (PACKED 8MB), out accC stride 28; 5 lanes x 51 rows
    run_layer<20, 27, 20, 28, 4, 5, 51>(45, accB, W3, accC, t0, t1, t2, rp_dst, packed, stream);
    // final fuses silu(acc+b3) + W4 dot + sigmoid — no silu_bias<27,28> pass.
    final_kernel<<<gN, BS, 0, stream>>>(accC, b3, W4, out);
}